// Round 3
// baseline (381.099 us; speedup 1.0000x reference)
//
#include <hip/hip_runtime.h>
#include <math.h>

// Caffe-style RPN proposal layer on gfx950.
// scores (1,64,64,18) f32 + deltas (1,64,64,36) f32 -> (300,4) f32.
// Pipeline:
//   memset ghist2 -> decode(+16-bit hist) -> select_compact (threshold+compact)
//   -> rank_gather (grid-parallel exact ranking, scatter to sorted order)
//   -> nms_mask (triangular IoU bitmask) -> nms_scan (parallel-apply greedy, fused output)

#define NPROP   36864
#define TOPN    6000
#define POSTN   300
#define NWORDS  94          // ceil(6000/64)
#define MAXSEL  8192
#define NEGINF_PAT 0x007FFFFFu   // sortable pattern of -inf score

typedef unsigned long long u64;

// classic 9 anchors for base=16, ratios {0.5,1,2}, scales {8,16,32}
__constant__ float ANCH[9][4] = {
    {-84.f,  -40.f,  99.f,  55.f},
    {-176.f, -88.f,  191.f, 103.f},
    {-360.f, -184.f, 375.f, 199.f},
    {-56.f,  -56.f,  71.f,  71.f},
    {-120.f, -120.f, 135.f, 135.f},
    {-248.f, -248.f, 263.f, 263.f},
    {-36.f,  -80.f,  51.f,  95.f},
    {-80.f,  -168.f, 95.f,  183.f},
    {-168.f, -344.f, 183.f, 359.f},
};

// ---------- decode + sortable key-high + 16-bit-bucket global histogram ----------
__global__ __launch_bounds__(256) void decode_kernel(
        const float* __restrict__ scores,
        const float* __restrict__ deltas,
        float4* __restrict__ boxes,
        unsigned* __restrict__ uhigh,
        unsigned* __restrict__ ghist2) {
    int i = blockIdx.x * 256 + threadIdx.x;   // exactly NPROP threads
    int a   = i % 9;
    int pos = i / 9;
    int wx = pos & 63, hy = pos >> 6;
    float sx = (float)(wx * 16), sy = (float)(hy * 16);

    float ax1 = ANCH[a][0] + sx, ay1 = ANCH[a][1] + sy;
    float ax2 = ANCH[a][2] + sx, ay2 = ANCH[a][3] + sy;
    float aw  = ax2 - ax1 + 1.0f;
    float ah  = ay2 - ay1 + 1.0f;
    float acx = ax1 + 0.5f * aw;
    float acy = ay1 + 0.5f * ah;

    const float* d = deltas + ((size_t)pos * 36 + a * 4);
    float dx = d[0], dy = d[1], dw = d[2], dh = d[3];
    float fg = scores[(size_t)pos * 18 + 9 + a];

    // match unfused numpy rounding: block FMA contraction
    float pcx = __fadd_rn(__fmul_rn(dx, aw), acx);
    float pcy = __fadd_rn(__fmul_rn(dy, ah), acy);
    float pw  = __fmul_rn(expf(dw), aw);
    float ph  = __fmul_rn(expf(dh), ah);
    float hx  = __fmul_rn(0.5f, pw);
    float hv  = __fmul_rn(0.5f, ph);

    float x1 = fminf(fmaxf(__fsub_rn(pcx, hx), 0.0f), 1023.0f);
    float y1 = fminf(fmaxf(__fsub_rn(pcy, hv), 0.0f), 1023.0f);
    float x2 = fminf(fmaxf(__fadd_rn(pcx, hx), 0.0f), 1023.0f);
    float y2 = fminf(fmaxf(__fadd_rn(pcy, hv), 0.0f), 1023.0f);

    float bw = __fadd_rn(__fsub_rn(x2, x1), 1.0f);
    float bh = __fadd_rn(__fsub_rn(y2, y1), 1.0f);
    bool valid = (bw >= 16.0f) && (bh >= 16.0f);
    float sc = valid ? fg : -__builtin_huge_valf();

    boxes[i] = make_float4(x1, y1, x2, y2);

    unsigned u = __float_as_uint(sc);
    u = (u & 0x80000000u) ? ~u : (u | 0x80000000u);   // sortable: bigger = better
    uhigh[i] = u;
    atomicAdd(&ghist2[u >> 16], 1u);
}

// ---------- find 16-bit-granular threshold, compact candidates ----------
__global__ __launch_bounds__(1024) void select_compact(
        const unsigned* __restrict__ ghist2,
        const unsigned* __restrict__ uhigh,
        u64* __restrict__ sel,
        unsigned* __restrict__ nsel) {
    __shared__ unsigned strip[1024];
    __shared__ unsigned thr_sh;
    __shared__ unsigned cnt_sh;
    int t = threadIdx.x;
    unsigned s = 0;
    #pragma unroll 4
    for (int k = 0; k < 64; ++k) s += ghist2[t * 64 + k];
    strip[t] = s;
    if (t == 0) cnt_sh = 0;
    __syncthreads();
    if (t == 0) {
        unsigned acc = 0; int si = 1023;
        for (; si >= 0; --si) { acc += strip[si]; if (acc >= TOPN) break; }
        if (si < 0) si = 0;
        unsigned acc2 = acc - strip[si];
        int b = 63;
        for (; b >= 0; --b) { acc2 += ghist2[si * 64 + b]; if (acc2 >= TOPN) break; }
        if (b < 0) b = 0;
        thr_sh = (unsigned)(si * 64 + b);
    }
    __syncthreads();
    unsigned thr = thr_sh << 16;   // count(uhigh >= thr) >= TOPN by construction
    for (int i = t; i < NPROP; i += 1024) {
        unsigned u = uhigh[i];
        if (u >= thr) {
            unsigned p = atomicAdd(&cnt_sh, 1u);
            if (p < MAXSEL)
                sel[p] = ((u64)u << 32) | (u64)(0xFFFFFFFFu - (unsigned)i);
        }
    }
    __syncthreads();
    if (t == 0) *nsel = (cnt_sh > MAXSEL) ? MAXSEL : cnt_sh;
}

// ---------- grid-parallel exact ranking + scatter to sorted order ----------
__global__ __launch_bounds__(256) void rank_gather(
        const u64* __restrict__ sel,
        const unsigned* __restrict__ nsel,
        const float4* __restrict__ boxes,
        float4* __restrict__ topb,
        float* __restrict__ areas,
        unsigned* __restrict__ topu) {
    __shared__ u64 tile[256];
    int t = threadIdx.x;
    int j = blockIdx.x * 256 + t;
    int n = (int)*nsel;
    u64 myk = (j < n) ? sel[j] : 0ULL;
    int rank = 0;
    for (int base = 0; base < n; base += 256) {
        int m = min(256, n - base);
        if (t < m) tile[t] = sel[base + t];
        __syncthreads();
        for (int q = 0; q < m; ++q) rank += (tile[q] > myk) ? 1 : 0;
        __syncthreads();
    }
    if (j < n && rank < TOPN) {
        unsigned idx = 0xFFFFFFFFu - (unsigned)(myk & 0xFFFFFFFFull);
        float4 b = boxes[idx];
        topb[rank] = b;
        areas[rank] = __fmul_rn(__fadd_rn(__fsub_rn(b.z, b.x), 1.0f),
                                __fadd_rn(__fsub_rn(b.w, b.y), 1.0f));
        topu[rank] = (unsigned)(myk >> 32);
    }
}

// ---------- NMS suppression bit-matrix (upper triangle incl. diagonal) ----------
__global__ void nms_mask(const float4* __restrict__ boxes,
                         const float* __restrict__ areas,
                         u64* __restrict__ mask) {
    int rb = blockIdx.x, cb = blockIdx.y;
    if (cb < rb) return;                       // j > i only; sub-diagonal unwritten
    __shared__ float4 cbx[64];
    __shared__ float  car[64];
    int tid = threadIdx.x;
    int j0 = cb * 64;
    if (j0 + tid < TOPN) { cbx[tid] = boxes[j0 + tid]; car[tid] = areas[j0 + tid]; }
    __syncthreads();
    int i = rb * 64 + tid;
    if (i >= TOPN) return;
    float4 bi = boxes[i];
    float  ai = areas[i];
    u64 bits = 0ULL;
    int jmax = min(64, TOPN - j0);
    for (int jj = 0; jj < jmax; ++jj) {
        int j = j0 + jj;
        if (j <= i) continue;
        float4 bj = cbx[jj];
        float xx1 = fmaxf(bi.x, bj.x);
        float yy1 = fmaxf(bi.y, bj.y);
        float xx2 = fminf(bi.z, bj.z);
        float yy2 = fminf(bi.w, bj.w);
        float w = fmaxf(__fadd_rn(__fsub_rn(xx2, xx1), 1.0f), 0.0f);
        float h = fmaxf(__fadd_rn(__fsub_rn(yy2, yy1), 1.0f), 0.0f);
        float inter = __fmul_rn(w, h);
        float denom = __fsub_rn(__fadd_rn(ai, car[jj]), inter);
        float iou = inter / denom;
        if (iou > 0.5f) bits |= (1ULL << jj);
    }
    mask[(size_t)i * NWORDS + cb] = bits;
}

// ---------- greedy scan with parallel row-apply + fused output ----------
// 1024 threads (16 waves). Removed-state in LDS (2x32-bit words per chunk).
// Per chunk: wave0 resolves in-register (ctz+shfl per KEPT box), then waves
// 0..14 apply all kept rows' future words in ONE latency window (one thread
// per (kept,word) pair), while wave15 prefetches next chunk's diagonal words
// + finiteness flags into LDS. -inf boxes suppress but are excluded from
// output (ref applies isfinite AFTER nms). Early exit at 300 finite kept.
__global__ __launch_bounds__(1024) void nms_scan(
        const unsigned* __restrict__ topu,
        const u64* __restrict__ mask,
        const float4* __restrict__ topb,
        float* __restrict__ out) {
    __shared__ unsigned rem32[NWORDS * 2];
    __shared__ u64 selfb[2][64];
    __shared__ unsigned sub[2][64];
    __shared__ u64 keptw_sh;
    __shared__ int nkept_sh;
    __shared__ unsigned char kept_pos[64];
    __shared__ short kept_list[POSTN];
    __shared__ int cnt_sh;

    int t = threadIdx.x, wave = t >> 6, lane = t & 63;
    if (t < NWORDS * 2) rem32[t] = 0;
    if (t == 0) cnt_sh = 0;
    if (t < 64) {   // preload chunk 0 diagonal + flags
        selfb[0][t] = mask[(size_t)t * NWORDS + 0];
        sub[0][t]   = topu[t];
    }
    __syncthreads();

    for (int c = 0; c < NWORDS; ++c) {
        int i0 = c * 64;
        int p  = c & 1;
        if (wave == 0) {
            int nbox = min(64, TOPN - i0);
            u64 validm = (nbox == 64) ? ~0ULL : ((1ULL << nbox) - 1ULL);
            u64 R = (u64)rem32[2 * c] | ((u64)rem32[2 * c + 1] << 32);
            u64 selfmask = selfb[p][lane];
            unsigned su  = sub[p][lane];
            u64 F = __ballot(su != NEGINF_PAT);
            u64 aliveC = (~R) & validm;
            u64 keptw = 0ULL;
            while (aliveC) {
                int ii = __builtin_ctzll(aliveC);
                keptw |= (1ULL << ii);
                u64 row = __shfl(selfmask, ii, 64);
                aliveC &= ~(1ULL << ii);
                aliveC &= ~row;
            }
            if (lane == 0) {
                keptw_sh = keptw;
                int nk = 0;
                int cc = cnt_sh;
                u64 k2 = keptw;
                while (k2) {
                    int ii = __builtin_ctzll(k2); k2 &= k2 - 1ULL;
                    kept_pos[nk++] = (unsigned char)ii;
                    if (((F >> ii) & 1ULL) && cc < POSTN)
                        kept_list[cc++] = (short)(i0 + ii);
                }
                nkept_sh = nk;
                cnt_sh = cc;
            }
        }
        __syncthreads();

        int nk   = nkept_sh;
        int left = NWORDS - 1 - c;          // only future words c+1..93 matter
        if (wave == 15) {
            if (c + 1 < NWORDS) {
                int i1 = i0 + 64;
                bool v = (i1 + lane) < TOPN;
                selfb[p ^ 1][lane] = v ? mask[(size_t)(i1 + lane) * NWORDS + (c + 1)] : 0ULL;
                sub[p ^ 1][lane]   = v ? topu[i1 + lane] : NEGINF_PAT;
            }
        } else if (left > 0 && nk > 0) {
            int tot = nk * left;
            for (int q = t; q < tot; q += 960) {
                int k  = q / left;
                int wd = c + 1 + (q - k * left);
                int row = i0 + (int)kept_pos[k];
                u64 v = mask[(size_t)row * NWORDS + wd];
                unsigned lo = (unsigned)v, hi = (unsigned)(v >> 32);
                if (lo) atomicOr(&rem32[2 * wd],     lo);
                if (hi) atomicOr(&rem32[2 * wd + 1], hi);
            }
        }
        __syncthreads();
        if (cnt_sh >= POSTN) break;
    }

    // fused output: first 300 kept (rank order), /1024, zero-fill rest
    int c = cnt_sh;
    if (t < POSTN) {
        float4 v = make_float4(0.f, 0.f, 0.f, 0.f);
        if (t < c) {
            float4 b = topb[kept_list[t]];
            v = make_float4(b.x * 0.0009765625f, b.y * 0.0009765625f,
                            b.z * 0.0009765625f, b.w * 0.0009765625f);
        }
        ((float4*)out)[t] = v;
    }
}

extern "C" void kernel_launch(void* const* d_in, const int* in_sizes, int n_in,
                              void* d_out, int out_size, void* d_ws, size_t ws_size,
                              hipStream_t stream) {
    const float* scores = (const float*)d_in[0];   // (1,64,64,18)
    const float* deltas = (const float*)d_in[1];   // (1,64,64,36)
    float* out = (float*)d_out;                    // 300*4

    // workspace layout (mask overlays ghist2/sel/nsel, which die before nms_mask)
    char* w = (char*)d_ws;
    float4*   boxes  = (float4*)(w);                   //       0 .. 589824
    unsigned* uhigh  = (unsigned*)(w + 589824);        //  589824 .. 737280
    unsigned* ghist2 = (unsigned*)(w + 737280);        //  737280 .. 999424 (dead after select)
    u64*      sel    = (u64*)(w + 999424);             //  999424 .. 1064960 (dead after rank)
    unsigned* nsel   = (unsigned*)(w + 1064960);       // 1064960 .. 1064976 (dead after rank)
    u64*      mask   = (u64*)(w + 737280);             //  737280 .. 5249280 (overlays the above)
    float4*   topb   = (float4*)(w + 5249280);         // 5249280 .. 5345280
    float*    areas  = (float*)(w + 5345280);          // 5345280 .. 5369280
    unsigned* topu   = (unsigned*)(w + 5369280);       // 5369280 .. 5393280

    hipMemsetAsync(ghist2, 0, 65536 * sizeof(unsigned), stream);
    decode_kernel<<<NPROP / 256, 256, 0, stream>>>(scores, deltas, boxes, uhigh, ghist2);
    select_compact<<<1, 1024, 0, stream>>>(ghist2, uhigh, sel, nsel);
    rank_gather<<<MAXSEL / 256, 256, 0, stream>>>(sel, nsel, boxes, topb, areas, topu);
    nms_mask<<<dim3(NWORDS, NWORDS), 64, 0, stream>>>(topb, areas, mask);
    nms_scan<<<1, 1024, 0, stream>>>(topu, mask, topb, out);
}

// Round 4
// 186.204 us; speedup vs baseline: 2.0467x; 2.0467x over previous
//
#include <hip/hip_runtime.h>
#include <math.h>

// Caffe-style RPN proposal layer on gfx950.
// scores (1,64,64,18) f32 + deltas (1,64,64,36) f32 -> (300,4) f32.
// Pipeline (5 kernels, no memsets, no global-atomic hot spots):
//   decode -> select_compact (LDS 14-bit hist threshold + compact)
//   -> rank_partial (8-way split exact ranking) -> scatter_top
//   -> nms_scan (LDS-resident on-the-fly-IoU greedy NMS, fused output)

#define NPROP   36864
#define TOPN    6000
#define POSTN   300
#define NCHUNK  94          // ceil(6000/64)
#define MAXSEL  8192
#define NB      16384       // 14-bit histogram buckets
#define SPLIT   8
#define KCAP    512
#define NEGINF_PAT 0x007FFFFFu   // sortable pattern of -inf score

typedef unsigned long long u64;

// classic 9 anchors for base=16, ratios {0.5,1,2}, scales {8,16,32}
__constant__ float ANCH[9][4] = {
    {-84.f,  -40.f,  99.f,  55.f},
    {-176.f, -88.f,  191.f, 103.f},
    {-360.f, -184.f, 375.f, 199.f},
    {-56.f,  -56.f,  71.f,  71.f},
    {-120.f, -120.f, 135.f, 135.f},
    {-248.f, -248.f, 263.f, 263.f},
    {-36.f,  -80.f,  51.f,  95.f},
    {-80.f,  -168.f, 95.f,  183.f},
    {-168.f, -344.f, 183.f, 359.f},
};

__device__ __forceinline__ float box_area(float4 b) {
    return __fmul_rn(__fadd_rn(__fsub_rn(b.z, b.x), 1.0f),
                     __fadd_rn(__fsub_rn(b.w, b.y), 1.0f));
}

__device__ __forceinline__ float iou_fn(float4 a, float aa, float4 b, float ab) {
    float xx1 = fmaxf(a.x, b.x);
    float yy1 = fmaxf(a.y, b.y);
    float xx2 = fminf(a.z, b.z);
    float yy2 = fminf(a.w, b.w);
    float w = fmaxf(__fadd_rn(__fsub_rn(xx2, xx1), 1.0f), 0.0f);
    float h = fmaxf(__fadd_rn(__fsub_rn(yy2, yy1), 1.0f), 0.0f);
    float inter = __fmul_rn(w, h);
    return inter / __fsub_rn(__fadd_rn(aa, ab), inter);
}

// ---------- decode: boxes + sortable score-high word (no histogram) ----------
__global__ __launch_bounds__(256) void decode_kernel(
        const float* __restrict__ scores,
        const float* __restrict__ deltas,
        float4* __restrict__ boxes,
        unsigned* __restrict__ uhigh) {
    int i = blockIdx.x * 256 + threadIdx.x;   // exactly NPROP threads
    int a   = i % 9;
    int pos = i / 9;
    int wx = pos & 63, hy = pos >> 6;
    float sx = (float)(wx * 16), sy = (float)(hy * 16);

    float ax1 = ANCH[a][0] + sx, ay1 = ANCH[a][1] + sy;
    float ax2 = ANCH[a][2] + sx, ay2 = ANCH[a][3] + sy;
    float aw  = ax2 - ax1 + 1.0f;
    float ah  = ay2 - ay1 + 1.0f;
    float acx = ax1 + 0.5f * aw;
    float acy = ay1 + 0.5f * ah;

    // deltas offset = (pos*36 + a*4) floats = i*4 floats -> 16B aligned float4
    float4 d4 = ((const float4*)deltas)[i];
    float fg = scores[(size_t)pos * 18 + 9 + a];

    // match unfused numpy rounding: block FMA contraction
    float pcx = __fadd_rn(__fmul_rn(d4.x, aw), acx);
    float pcy = __fadd_rn(__fmul_rn(d4.y, ah), acy);
    float pw  = __fmul_rn(expf(d4.z), aw);
    float ph  = __fmul_rn(expf(d4.w), ah);
    float hx  = __fmul_rn(0.5f, pw);
    float hv  = __fmul_rn(0.5f, ph);

    float x1 = fminf(fmaxf(__fsub_rn(pcx, hx), 0.0f), 1023.0f);
    float y1 = fminf(fmaxf(__fsub_rn(pcy, hv), 0.0f), 1023.0f);
    float x2 = fminf(fmaxf(__fadd_rn(pcx, hx), 0.0f), 1023.0f);
    float y2 = fminf(fmaxf(__fadd_rn(pcy, hv), 0.0f), 1023.0f);

    float bw = __fadd_rn(__fsub_rn(x2, x1), 1.0f);
    float bh = __fadd_rn(__fsub_rn(y2, y1), 1.0f);
    bool valid = (bw >= 16.0f) && (bh >= 16.0f);
    float sc = valid ? fg : -__builtin_huge_valf();

    boxes[i] = make_float4(x1, y1, x2, y2);

    unsigned u = __float_as_uint(sc);
    u = (u & 0x80000000u) ? ~u : (u | 0x80000000u);   // sortable: bigger = better
    uhigh[i] = u;
}

// ---------- single-block: LDS histogram threshold + register-held compact ----------
__global__ __launch_bounds__(1024) void select_compact(
        const unsigned* __restrict__ uhigh,
        u64* __restrict__ sel,
        unsigned* __restrict__ nsel,
        int* __restrict__ rank) {
    __shared__ unsigned hist[NB];      // 64 KB
    __shared__ unsigned strip[1024];
    __shared__ unsigned thr_sh, cnt_sh;
    int t = threadIdx.x;
    #pragma unroll
    for (int r = 0; r < NB / 1024; ++r) hist[t + r * 1024] = 0;
    if (t == 0) cnt_sh = 0;
    __syncthreads();

    unsigned v[36];                    // NPROP/1024 == 36
    #pragma unroll
    for (int r = 0; r < 36; ++r) v[r] = uhigh[t + r * 1024];
    #pragma unroll
    for (int r = 0; r < 36; ++r) atomicAdd(&hist[v[r] >> 18], 1u);
    __syncthreads();

    unsigned s = 0;
    #pragma unroll
    for (int k = 0; k < 16; ++k) s += hist[t * 16 + k];
    strip[t] = s;
    __syncthreads();
    if (t == 0) {
        int si = 1023; unsigned acc = 0;
        for (;;) { acc += strip[si]; if (acc >= TOPN || si == 0) break; --si; }
        unsigned acc2 = acc - strip[si];
        int b = 15;
        for (;;) { acc2 += hist[si * 16 + b]; if (acc2 >= TOPN || b == 0) break; --b; }
        thr_sh = (unsigned)(si * 16 + b);
    }
    __syncthreads();
    unsigned thr = thr_sh << 18;       // count(uhigh >= thr) >= TOPN by construction
    #pragma unroll
    for (int r = 0; r < 36; ++r) {
        if (v[r] >= thr) {
            unsigned p = atomicAdd(&cnt_sh, 1u);
            if (p < MAXSEL)
                sel[p] = ((u64)v[r] << 32) |
                         (u64)(0xFFFFFFFFu - (unsigned)(t + r * 1024));
        }
    }
    for (int r = t; r < MAXSEL; r += 1024) rank[r] = 0;   // zero rank array
    __syncthreads();
    if (t == 0) *nsel = (cnt_sh > MAXSEL) ? MAXSEL : cnt_sh;
}

// ---------- exact rank by counting, inner dim split SPLIT ways ----------
__global__ __launch_bounds__(256) void rank_partial(
        const u64* __restrict__ sel,
        const unsigned* __restrict__ nsel,
        int* __restrict__ rank) {
    __shared__ u64 tile[1024];
    int t = threadIdx.x;
    int j = blockIdx.x * 256 + t;
    int n = (int)*nsel;
    int T = (n + SPLIT - 1) / SPLIT;
    int lo = blockIdx.y * T;
    int hi = min(lo + T, n);
    u64 myk = (j < n) ? sel[j] : 0ULL;
    int rk = 0;
    for (int base = lo; base < hi; base += 1024) {
        int m = min(1024, hi - base);
        for (int q = t; q < m; q += 256) tile[q] = sel[base + q];
        __syncthreads();
        for (int q = 0; q < m; ++q) rk += (tile[q] > myk) ? 1 : 0;
        __syncthreads();
    }
    if (j < n && rk > 0) atomicAdd(&rank[j], rk);
}

__global__ __launch_bounds__(256) void scatter_top(
        const u64* __restrict__ sel,
        const unsigned* __restrict__ nsel,
        const int* __restrict__ rank,
        const float4* __restrict__ boxes,
        float4* __restrict__ topb,
        unsigned* __restrict__ topu) {
    int j = blockIdx.x * 256 + threadIdx.x;
    int n = (int)*nsel;
    if (j >= n) return;
    int r = rank[j];
    if (r >= TOPN) return;
    u64 k = sel[j];
    unsigned idx = 0xFFFFFFFFu - (unsigned)(k & 0xFFFFFFFFull);
    topb[r] = boxes[idx];
    topu[r] = (unsigned)(k >> 32);
}

// ---------- greedy NMS, everything in LDS, IoU on the fly ----------
// 1024 thr. Kept boxes (incl. -inf ones, which suppress but aren't output)
// accumulate in LDS. Per 64-candidate chunk: waves 0-14 compute suppression
// vs all kept (ballot->S) and the 64x64 intra-chunk bit matrix; wave 15
// prefetches next chunk; wave 0 resolves greedily from LDS only.
__global__ __launch_bounds__(1024) void nms_scan(
        const float4* __restrict__ topb,
        const unsigned* __restrict__ topu,
        float* __restrict__ out) {
    __shared__ float4 kbox[KCAP];
    __shared__ float  karea[KCAP];
    __shared__ float4 cbox[2][64];
    __shared__ float  carea[2][64];
    __shared__ unsigned cu[2][64];
    __shared__ unsigned Slo, Shi;
    __shared__ u64 intra[64];
    __shared__ short kept_list[POSTN];
    __shared__ int nkept_sh;   // total kept incl. -inf
    __shared__ int cnt_sh;     // finite kept (output count)

    int t = threadIdx.x, wave = t >> 6, lane = t & 63;
    if (t == 0) { nkept_sh = 0; cnt_sh = 0; Slo = 0; Shi = 0; }
    if (t < 64) {
        float4 b = topb[t];
        cbox[0][t] = b;
        carea[0][t] = box_area(b);
        cu[0][t] = topu[t];
    }
    __syncthreads();

    for (int c = 0; c < NCHUNK; ++c) {
        int p = c & 1;
        int i0 = c * 64;
        int nbox = min(64, TOPN - i0);
        int nk = nkept_sh;

        if (wave == 15) {
            if (c + 1 < NCHUNK) {
                int i1 = i0 + 64;
                bool vld = (i1 + lane) < TOPN;
                float4 b = vld ? topb[i1 + lane] : make_float4(0.f, 0.f, 0.f, 0.f);
                cbox[p ^ 1][lane] = b;
                carea[p ^ 1][lane] = box_area(b);
                cu[p ^ 1][lane] = vld ? topu[i1 + lane] : NEGINF_PAT;
            }
        } else {
            float4 bj = cbox[p][lane];
            float  aj = carea[p][lane];
            // phase A: suppression by previously-kept boxes
            bool supp = false;
            for (int k = wave; k < nk; k += 15) {
                float iou = iou_fn(bj, aj, kbox[k], karea[k]);
                supp |= (iou > 0.5f);
            }
            u64 ball = __ballot(supp);
            if (lane == 0 && ball) {
                unsigned blo = (unsigned)ball, bhi = (unsigned)(ball >> 32);
                if (blo) atomicOr(&Slo, blo);
                if (bhi) atomicOr(&Shi, bhi);
            }
            // phase B: intra-chunk bit rows (j > r)
            for (int r = wave; r < nbox; r += 15) {
                float iou = iou_fn(cbox[p][r], carea[p][r], bj, aj);
                u64 bits = __ballot(iou > 0.5f);
                if (lane == 0) intra[r] = bits & ~((2ULL << r) - 1ULL);
            }
        }
        __syncthreads();

        if (wave == 0) {
            u64 S = (u64)Slo | ((u64)Shi << 32);
            u64 F = __ballot(cu[p][lane] != NEGINF_PAT);
            u64 validm = (nbox == 64) ? ~0ULL : ((1ULL << nbox) - 1ULL);
            u64 aliveC = ~S & validm;
            u64 keptw = 0ULL;
            while (aliveC) {
                int ii = __builtin_ctzll(aliveC);
                keptw |= (1ULL << ii);
                u64 row = intra[ii];
                aliveC &= ~(1ULL << ii);
                aliveC &= ~row;
            }
            int nsurv = __popcll(keptw);
            if (lane < nsurv) {     // parallel append of survivors
                u64 w2 = keptw;
                for (int z = 0; z < lane; ++z) w2 &= w2 - 1ULL;
                int ii = __builtin_ctzll(w2);
                int pos = nkept_sh + lane;
                if (pos < KCAP) {
                    kbox[pos]  = cbox[p][ii];
                    karea[pos] = carea[p][ii];
                }
            }
            if (lane == 0) {
                int base = nkept_sh, cc = cnt_sh, m = 0;
                u64 k2 = keptw;
                while (k2) {
                    int ii = __builtin_ctzll(k2); k2 &= k2 - 1ULL;
                    if (((F >> ii) & 1ULL) && cc < POSTN && (base + m) < KCAP)
                        kept_list[cc++] = (short)(base + m);
                    ++m;
                }
                nkept_sh = min(base + m, KCAP);
                cnt_sh = cc;
                Slo = 0; Shi = 0;
            }
        }
        __syncthreads();
        if (cnt_sh >= POSTN) break;
    }

    // fused output: first 300 kept, /1024, zero-fill rest
    if (t < POSTN) {
        float4 v = make_float4(0.f, 0.f, 0.f, 0.f);
        if (t < cnt_sh) {
            float4 b = kbox[kept_list[t]];
            const float s = 0.0009765625f;   // 1/1024 (exact)
            v = make_float4(b.x * s, b.y * s, b.z * s, b.w * s);
        }
        ((float4*)out)[t] = v;
    }
}

extern "C" void kernel_launch(void* const* d_in, const int* in_sizes, int n_in,
                              void* d_out, int out_size, void* d_ws, size_t ws_size,
                              hipStream_t stream) {
    const float* scores = (const float*)d_in[0];   // (1,64,64,18)
    const float* deltas = (const float*)d_in[1];   // (1,64,64,36)
    float* out = (float*)d_out;                    // 300*4

    char* w = (char*)d_ws;
    float4*   boxes = (float4*)(w);                 //      0 .. 589824
    unsigned* uhigh = (unsigned*)(w + 589824);      // 589824 .. 737280
    u64*      sel   = (u64*)(w + 737280);           // 737280 .. 802816
    unsigned* nsel  = (unsigned*)(w + 802816);      // 802816 .. 802832
    int*      rank  = (int*)(w + 802832);           // 802832 .. 835600
    float4*   topb  = (float4*)(w + 835600);        // 835600 .. 931600
    unsigned* topu  = (unsigned*)(w + 931600);      // 931600 .. 955600

    decode_kernel<<<NPROP / 256, 256, 0, stream>>>(scores, deltas, boxes, uhigh);
    select_compact<<<1, 1024, 0, stream>>>(uhigh, sel, nsel, rank);
    rank_partial<<<dim3(MAXSEL / 256, SPLIT), 256, 0, stream>>>(sel, nsel, rank);
    scatter_top<<<MAXSEL / 256, 256, 0, stream>>>(sel, nsel, rank, boxes, topb, topu);
    nms_scan<<<1, 1024, 0, stream>>>(topb, topu, out);
}

// Round 5
// 184.993 us; speedup vs baseline: 2.0601x; 1.0065x over previous
//
#include <hip/hip_runtime.h>
#include <math.h>

// Caffe-style RPN proposal layer on gfx950.
// scores (1,64,64,18) f32 + deltas (1,64,64,36) f32 -> (300,4) f32.
// Pipeline (6 kernels):
//   decode -> select_compact (LDS hist threshold + ballot-aggregated compact)
//   -> rank_partial (8-way split exact ranking, atomic-free) -> scatter_top
//   -> nms_mask (grid-parallel IoU bit matrix, upper triangle)
//   -> nms_scan (128-box rounds: shfl resolve + parallel row-apply, fused output)

#define NPROP   36864
#define TOPN    6000
#define POSTN   300
#define NWORDS  94          // ceil(6000/64)
#define NROUND  47          // ceil(6000/128)
#define MAXSEL  8192
#define NB      16384       // 14-bit histogram buckets
#define SPLIT   8
#define NEGINF_PAT 0x007FFFFFu   // sortable pattern of -inf score

typedef unsigned long long u64;

// classic 9 anchors for base=16, ratios {0.5,1,2}, scales {8,16,32}
__constant__ float ANCH[9][4] = {
    {-84.f,  -40.f,  99.f,  55.f},
    {-176.f, -88.f,  191.f, 103.f},
    {-360.f, -184.f, 375.f, 199.f},
    {-56.f,  -56.f,  71.f,  71.f},
    {-120.f, -120.f, 135.f, 135.f},
    {-248.f, -248.f, 263.f, 263.f},
    {-36.f,  -80.f,  51.f,  95.f},
    {-80.f,  -168.f, 95.f,  183.f},
    {-168.f, -344.f, 183.f, 359.f},
};

__device__ __forceinline__ float box_area(float4 b) {
    return __fmul_rn(__fadd_rn(__fsub_rn(b.z, b.x), 1.0f),
                     __fadd_rn(__fsub_rn(b.w, b.y), 1.0f));
}

// ---------- decode: boxes + sortable score-high word ----------
__global__ __launch_bounds__(256) void decode_kernel(
        const float* __restrict__ scores,
        const float* __restrict__ deltas,
        float4* __restrict__ boxes,
        unsigned* __restrict__ uhigh) {
    int i = blockIdx.x * 256 + threadIdx.x;   // exactly NPROP threads
    int a   = i % 9;
    int pos = i / 9;
    int wx = pos & 63, hy = pos >> 6;
    float sx = (float)(wx * 16), sy = (float)(hy * 16);

    float ax1 = ANCH[a][0] + sx, ay1 = ANCH[a][1] + sy;
    float ax2 = ANCH[a][2] + sx, ay2 = ANCH[a][3] + sy;
    float aw  = ax2 - ax1 + 1.0f;
    float ah  = ay2 - ay1 + 1.0f;
    float acx = ax1 + 0.5f * aw;
    float acy = ay1 + 0.5f * ah;

    // deltas offset = (pos*36 + a*4) floats = i*4 floats -> 16B-aligned float4
    float4 d4 = ((const float4*)deltas)[i];
    float fg = scores[(size_t)pos * 18 + 9 + a];

    // match unfused numpy rounding: block FMA contraction
    float pcx = __fadd_rn(__fmul_rn(d4.x, aw), acx);
    float pcy = __fadd_rn(__fmul_rn(d4.y, ah), acy);
    float pw  = __fmul_rn(expf(d4.z), aw);
    float ph  = __fmul_rn(expf(d4.w), ah);
    float hx  = __fmul_rn(0.5f, pw);
    float hv  = __fmul_rn(0.5f, ph);

    float x1 = fminf(fmaxf(__fsub_rn(pcx, hx), 0.0f), 1023.0f);
    float y1 = fminf(fmaxf(__fsub_rn(pcy, hv), 0.0f), 1023.0f);
    float x2 = fminf(fmaxf(__fadd_rn(pcx, hx), 0.0f), 1023.0f);
    float y2 = fminf(fmaxf(__fadd_rn(pcy, hv), 0.0f), 1023.0f);

    float bw = __fadd_rn(__fsub_rn(x2, x1), 1.0f);
    float bh = __fadd_rn(__fsub_rn(y2, y1), 1.0f);
    bool valid = (bw >= 16.0f) && (bh >= 16.0f);
    float sc = valid ? fg : -__builtin_huge_valf();

    boxes[i] = make_float4(x1, y1, x2, y2);

    unsigned u = __float_as_uint(sc);
    u = (u & 0x80000000u) ? ~u : (u | 0x80000000u);   // sortable: bigger = better
    uhigh[i] = u;
}

// ---------- single block: LDS hist threshold + wave-aggregated compact ----------
__global__ __launch_bounds__(1024) void select_compact(
        const unsigned* __restrict__ uhigh,
        u64* __restrict__ sel,
        unsigned* __restrict__ nsel) {
    __shared__ unsigned hist[NB];      // 64 KB
    __shared__ unsigned strip[1024];
    __shared__ unsigned group[64];
    __shared__ unsigned thr_sh, cnt_sh;
    int t = threadIdx.x, lane = t & 63;
    #pragma unroll
    for (int r = 0; r < NB / 1024; ++r) hist[t + r * 1024] = 0;
    if (t == 0) cnt_sh = 0;
    __syncthreads();

    unsigned v[36];                    // NPROP/1024 == 36
    #pragma unroll
    for (int r = 0; r < 36; ++r) v[r] = uhigh[t + r * 1024];
    #pragma unroll
    for (int r = 0; r < 36; ++r) atomicAdd(&hist[v[r] >> 18], 1u);
    __syncthreads();

    unsigned s = 0;
    #pragma unroll
    for (int k = 0; k < 16; ++k) s += hist[t * 16 + k];
    strip[t] = s;
    __syncthreads();
    if (t < 64) {
        unsigned g = 0;
        #pragma unroll
        for (int k = 0; k < 16; ++k) g += strip[t * 16 + k];
        group[t] = g;
    }
    __syncthreads();
    if (t == 0) {
        unsigned acc = 0; int g = 63;
        while (g > 0 && acc + group[g] < TOPN) { acc += group[g]; --g; }
        int si = g * 16 + 15;
        while (si > g * 16 && acc + strip[si] < TOPN) { acc += strip[si]; --si; }
        int b = si * 16 + 15;
        while (b > si * 16 && acc + hist[b] < TOPN) { acc += hist[b]; --b; }
        thr_sh = (unsigned)b;
    }
    __syncthreads();
    unsigned thr = thr_sh << 18;       // count(uhigh >= thr) >= TOPN by construction
    #pragma unroll
    for (int r = 0; r < 36; ++r) {
        bool pred = (v[r] >= thr);
        u64 b = __ballot(pred);
        int nb = __popcll(b);
        unsigned base = 0;
        if (lane == 0 && nb) base = atomicAdd(&cnt_sh, (unsigned)nb);
        base = __shfl(base, 0, 64);
        if (pred) {
            unsigned p = base + (unsigned)__popcll(b & ((1ULL << lane) - 1ULL));
            if (p < MAXSEL)
                sel[p] = ((u64)v[r] << 32) |
                         (u64)(0xFFFFFFFFu - (unsigned)(t + r * 1024));
        }
    }
    __syncthreads();
    if (t == 0) *nsel = (cnt_sh > MAXSEL) ? MAXSEL : cnt_sh;
}

// ---------- exact rank by counting, inner dim split SPLIT ways, atomic-free ----------
__global__ __launch_bounds__(256) void rank_partial(
        const u64* __restrict__ sel,
        const unsigned* __restrict__ nsel,
        int* __restrict__ rank8) {
    __shared__ u64 tile[1024];
    int t = threadIdx.x;
    int j = blockIdx.x * 256 + t;
    int n = (int)*nsel;
    int T = (n + SPLIT - 1) / SPLIT;
    int lo = blockIdx.y * T;
    int hi = min(lo + T, n);
    u64 myk = (j < n) ? sel[j] : 0ULL;
    int rk = 0;
    for (int base = lo; base < hi; base += 1024) {
        int m = min(1024, hi - base);
        for (int q = t; q < m; q += 256) tile[q] = sel[base + q];
        __syncthreads();
        #pragma unroll 4
        for (int q = 0; q < m; ++q) rk += (tile[q] > myk) ? 1 : 0;
        __syncthreads();
    }
    rank8[blockIdx.y * MAXSEL + j] = rk;
}

__global__ __launch_bounds__(256) void scatter_top(
        const u64* __restrict__ sel,
        const unsigned* __restrict__ nsel,
        const int* __restrict__ rank8,
        const float4* __restrict__ boxes,
        float4* __restrict__ topb,
        float* __restrict__ areas,
        unsigned* __restrict__ topu) {
    int j = blockIdx.x * 256 + threadIdx.x;
    int n = (int)*nsel;
    if (j >= n) return;
    int r = 0;
    #pragma unroll
    for (int s = 0; s < SPLIT; ++s) r += rank8[s * MAXSEL + j];
    if (r >= TOPN) return;
    u64 k = sel[j];
    unsigned idx = 0xFFFFFFFFu - (unsigned)(k & 0xFFFFFFFFull);
    float4 b = boxes[idx];
    topb[r] = b;
    areas[r] = box_area(b);
    topu[r] = (unsigned)(k >> 32);
}

// ---------- grid-parallel IoU suppression bit matrix (j > i only) ----------
__global__ void nms_mask(const float4* __restrict__ boxes,
                         const float* __restrict__ areas,
                         u64* __restrict__ mask) {
    int rb = blockIdx.x, cb = blockIdx.y;
    if (cb < rb) return;                       // sub-diagonal words never read
    __shared__ float4 cbx[64];
    __shared__ float  car[64];
    int tid = threadIdx.x;
    int j0 = cb * 64;
    if (j0 + tid < TOPN) { cbx[tid] = boxes[j0 + tid]; car[tid] = areas[j0 + tid]; }
    __syncthreads();
    int i = rb * 64 + tid;
    if (i >= TOPN) return;
    float4 bi = boxes[i];
    float  ai = areas[i];
    u64 bits = 0ULL;
    int jmax = min(64, TOPN - j0);
    for (int jj = 0; jj < jmax; ++jj) {
        int j = j0 + jj;
        if (j <= i) continue;
        float4 bj = cbx[jj];
        float xx1 = fmaxf(bi.x, bj.x);
        float yy1 = fmaxf(bi.y, bj.y);
        float xx2 = fminf(bi.z, bj.z);
        float yy2 = fminf(bi.w, bj.w);
        float w = fmaxf(__fadd_rn(__fsub_rn(xx2, xx1), 1.0f), 0.0f);
        float h = fmaxf(__fadd_rn(__fsub_rn(yy2, yy1), 1.0f), 0.0f);
        float inter = __fmul_rn(w, h);
        float denom = __fsub_rn(__fadd_rn(ai, car[jj]), inter);
        float iou = inter / denom;              // IEEE-exact, matches numpy
        if (iou > 0.5f) bits |= (1ULL << jj);
    }
    mask[(size_t)i * NWORDS + cb] = bits;
}

// ---------- greedy scan: 128-box rounds, shfl resolve + parallel apply ----------
// 1024 thr. rem state (94 u64 as 188 u32) in LDS. Per round r (rows
// [128r,128r+128), words 2r/2r+1): wave0 resolves in-register via shfl on the
// prefetched diagonal block; waves 0-14 then apply all kept rows' future words
// (>= 2r+2) in one parallel latency window (atomicOr into rem) while wave 15
// prefetches round r+1's diagonal block + finite flags. -inf boxes suppress
// but are excluded from output (ref applies isfinite AFTER nms).
__global__ __launch_bounds__(1024) void nms_scan(
        const u64* __restrict__ mask,
        const unsigned* __restrict__ topu,
        const float4* __restrict__ topb,
        float* __restrict__ out) {
    __shared__ unsigned rem32[NWORDS * 2];
    __shared__ u64 diag[2][128][2];
    __shared__ u64 Fsh[2][2];
    __shared__ short kept_rows[128];
    __shared__ short kept_list[POSTN];
    __shared__ int nk_sh, cnt_sh, stop_sh;

    int t = threadIdx.x, wave = t >> 6, lane = t & 63;
    if (t < NWORDS * 2) rem32[t] = 0;
    if (t == 0) { cnt_sh = 0; stop_sh = 0; }
    if (t < 128) {   // round-0 diagonal block (rows 0..127, words 0..1)
        diag[0][t][0] = (t < 64) ? mask[(size_t)t * NWORDS + 0] : 0ULL;
        diag[0][t][1] = mask[(size_t)t * NWORDS + 1];
    }
    if (wave == 0) {
        u64 f = __ballot(topu[lane] != NEGINF_PAT);
        if (lane == 0) Fsh[0][0] = f;
    } else if (wave == 1) {
        u64 f = __ballot(topu[64 + lane] != NEGINF_PAT);
        if (lane == 0) Fsh[0][1] = f;
    }
    __syncthreads();

    for (int r = 0; r < NROUND; ++r) {
        int p = r & 1;
        int i0 = r * 128;
        if (wave == 0) {
            u64 r0w0 = diag[p][lane][0];
            u64 r0w1 = diag[p][lane][1];
            u64 r1w1 = diag[p][64 + lane][1];
            u64 R0 = (u64)rem32[4 * r]     | ((u64)rem32[4 * r + 1] << 32);
            u64 R1 = (u64)rem32[4 * r + 2] | ((u64)rem32[4 * r + 3] << 32);
            int nb = min(128, TOPN - i0);           // 128 or 112 (last round)
            u64 v1 = (nb >= 128) ? ~0ULL : ((1ULL << (nb - 64)) - 1ULL);
            u64 a0 = ~R0;                           // first half always full
            u64 a1 = ~R1 & v1;
            u64 k0 = 0ULL, k1 = 0ULL;
            while (a0) {
                int ii = __builtin_ctzll(a0);
                u64 bit = 1ULL << ii;
                k0 |= bit;
                u64 s0 = __shfl(r0w0, ii, 64);
                u64 s1 = __shfl(r0w1, ii, 64);
                a0 &= ~(s0 | bit);
                a1 &= ~s1;
            }
            while (a1) {
                int ii = __builtin_ctzll(a1);
                u64 bit = 1ULL << ii;
                k1 |= bit;
                u64 s1 = __shfl(r1w1, ii, 64);
                a1 &= ~(s1 | bit);
            }
            if (lane == 0) {
                u64 F0 = Fsh[p][0], F1 = Fsh[p][1];
                int nk = 0, cc = cnt_sh;
                u64 w2 = k0;
                while (w2) {
                    int ii = __builtin_ctzll(w2); w2 &= w2 - 1ULL;
                    kept_rows[nk++] = (short)(i0 + ii);
                    if (((F0 >> ii) & 1ULL) && cc < POSTN) kept_list[cc++] = (short)(i0 + ii);
                }
                w2 = k1;
                while (w2) {
                    int ii = __builtin_ctzll(w2); w2 &= w2 - 1ULL;
                    kept_rows[nk++] = (short)(i0 + 64 + ii);
                    if (((F1 >> ii) & 1ULL) && cc < POSTN) kept_list[cc++] = (short)(i0 + 64 + ii);
                }
                nk_sh = nk;
                cnt_sh = cc;
                stop_sh = (cc >= POSTN) || (r == NROUND - 1);
            }
        }
        __syncthreads();
        if (stop_sh) break;

        int wbase = 2 * r + 2;
        if (wave == 15) {
            // prefetch round r+1 diagonal block + finite flags
            int i1 = i0 + 128;
            int ra = i1 + lane, rb2 = i1 + 64 + lane;
            diag[p ^ 1][lane][0]      = (ra  < TOPN) ? mask[(size_t)ra  * NWORDS + wbase]     : 0ULL;
            diag[p ^ 1][lane][1]      = (ra  < TOPN) ? mask[(size_t)ra  * NWORDS + wbase + 1] : 0ULL;
            diag[p ^ 1][64 + lane][0] = 0ULL;       // sub-diagonal word: structurally empty
            diag[p ^ 1][64 + lane][1] = (rb2 < TOPN) ? mask[(size_t)rb2 * NWORDS + wbase + 1] : 0ULL;
            u64 fa = __ballot((ra  < TOPN) ? (topu[ra]  != NEGINF_PAT) : false);
            u64 fb = __ballot((rb2 < TOPN) ? (topu[rb2] != NEGINF_PAT) : false);
            if (lane == 0) { Fsh[p ^ 1][0] = fa; Fsh[p ^ 1][1] = fb; }
        } else {
            // apply kept rows' future words in one parallel window
            int nk = nk_sh;
            for (int k = wave; k < nk; k += 15) {
                int row = kept_rows[k];
                size_t base = (size_t)row * NWORDS;
                int wd = wbase + lane;
                if (wd < NWORDS) {
                    u64 v2 = mask[base + wd];
                    if (v2) {
                        unsigned lo = (unsigned)v2, hi = (unsigned)(v2 >> 32);
                        if (lo) atomicOr(&rem32[2 * wd],     lo);
                        if (hi) atomicOr(&rem32[2 * wd + 1], hi);
                    }
                }
                wd += 64;
                if (wd < NWORDS) {
                    u64 v2 = mask[base + wd];
                    if (v2) {
                        unsigned lo = (unsigned)v2, hi = (unsigned)(v2 >> 32);
                        if (lo) atomicOr(&rem32[2 * wd],     lo);
                        if (hi) atomicOr(&rem32[2 * wd + 1], hi);
                    }
                }
            }
        }
        __syncthreads();
    }

    // fused output: first 300 kept (rank order), /1024, zero-fill rest
    if (t < POSTN) {
        float4 v = make_float4(0.f, 0.f, 0.f, 0.f);
        if (t < cnt_sh) {
            float4 b = topb[kept_list[t]];
            const float s = 0.0009765625f;   // 1/1024 (exact)
            v = make_float4(b.x * s, b.y * s, b.z * s, b.w * s);
        }
        ((float4*)out)[t] = v;
    }
}

extern "C" void kernel_launch(void* const* d_in, const int* in_sizes, int n_in,
                              void* d_out, int out_size, void* d_ws, size_t ws_size,
                              hipStream_t stream) {
    const float* scores = (const float*)d_in[0];   // (1,64,64,18)
    const float* deltas = (const float*)d_in[1];   // (1,64,64,36)
    float* out = (float*)d_out;                    // 300*4

    char* w = (char*)d_ws;
    float4*   boxes = (float4*)(w);                 //       0 ..  589824
    unsigned* uhigh = (unsigned*)(w + 589824);      //  589824 ..  737280
    u64*      sel   = (u64*)(w + 737280);           //  737280 ..  802816
    unsigned* nsel  = (unsigned*)(w + 802816);      //  802816 ..  802832
    int*      rank8 = (int*)(w + 802832);           //  802832 .. 1064976
    float4*   topb  = (float4*)(w + 1064976);       // 1064976 .. 1160976
    float*    areas = (float*)(w + 1160976);        // 1160976 .. 1184976
    unsigned* topu  = (unsigned*)(w + 1184976);     // 1184976 .. 1208976
    u64*      mask  = (u64*)(w + 1208976);          // 1208976 .. 5720976 (4.5 MB)

    decode_kernel<<<NPROP / 256, 256, 0, stream>>>(scores, deltas, boxes, uhigh);
    select_compact<<<1, 1024, 0, stream>>>(uhigh, sel, nsel);
    rank_partial<<<dim3(MAXSEL / 256, SPLIT), 256, 0, stream>>>(sel, nsel, rank8);
    scatter_top<<<MAXSEL / 256, 256, 0, stream>>>(sel, nsel, rank8, boxes, topb, areas, topu);
    nms_mask<<<dim3(NWORDS, NWORDS), 64, 0, stream>>>(topb, areas, mask);
    nms_scan<<<1, 1024, 0, stream>>>(mask, topu, topb, out);
}

// Round 6
// 145.163 us; speedup vs baseline: 2.6253x; 1.2744x over previous
//
#include <hip/hip_runtime.h>
#include <math.h>

// Caffe-style RPN proposal layer on gfx950.
// scores (1,64,64,18) f32 + deltas (1,64,64,36) f32 -> (300,4) f32.
// Pipeline (6 kernels):
//   decode (uhigh only) -> select_compact (LDS hist + ballot compact)
//   -> rank_partial (8-way split) -> scatter_top (re-decode selected boxes)
//   -> nms_mask (grid IoU bit matrix) -> nms_scan (latency-hidden greedy, fused out)

#define NPROP   36864
#define TOPN    6000
#define POSTN   300
#define NWORDS  94          // ceil(6000/64)
#define NROUND  47          // ceil(6000/128)
#define MAXSEL  8192
#define NB      16384       // 14-bit histogram buckets
#define SPLIT   8
#define NEGINF_PAT 0x007FFFFFu   // sortable pattern of -inf score

typedef unsigned long long u64;

// classic 9 anchors for base=16, ratios {0.5,1,2}, scales {8,16,32}
__constant__ float ANCH[9][4] = {
    {-84.f,  -40.f,  99.f,  55.f},
    {-176.f, -88.f,  191.f, 103.f},
    {-360.f, -184.f, 375.f, 199.f},
    {-56.f,  -56.f,  71.f,  71.f},
    {-120.f, -120.f, 135.f, 135.f},
    {-248.f, -248.f, 263.f, 263.f},
    {-36.f,  -80.f,  51.f,  95.f},
    {-80.f,  -168.f, 95.f,  183.f},
    {-168.f, -344.f, 183.f, 359.f},
};

// decode box for anchor-index i (match unfused numpy rounding: no FMA)
__device__ __forceinline__ float4 decode_box(const float* __restrict__ deltas, int i,
                                             bool* valid_out) {
    int a   = i % 9;
    int pos = i / 9;
    int wx = pos & 63, hy = pos >> 6;
    float sx = (float)(wx * 16), sy = (float)(hy * 16);
    float ax1 = ANCH[a][0] + sx, ay1 = ANCH[a][1] + sy;
    float ax2 = ANCH[a][2] + sx, ay2 = ANCH[a][3] + sy;
    float aw  = ax2 - ax1 + 1.0f;
    float ah  = ay2 - ay1 + 1.0f;
    float acx = ax1 + 0.5f * aw;
    float acy = ay1 + 0.5f * ah;
    float4 d4 = ((const float4*)deltas)[i];   // (pos*36+a*4) floats == i*4 floats
    float pcx = __fadd_rn(__fmul_rn(d4.x, aw), acx);
    float pcy = __fadd_rn(__fmul_rn(d4.y, ah), acy);
    float pw  = __fmul_rn(expf(d4.z), aw);
    float ph  = __fmul_rn(expf(d4.w), ah);
    float hx  = __fmul_rn(0.5f, pw);
    float hv  = __fmul_rn(0.5f, ph);
    float x1 = fminf(fmaxf(__fsub_rn(pcx, hx), 0.0f), 1023.0f);
    float y1 = fminf(fmaxf(__fsub_rn(pcy, hv), 0.0f), 1023.0f);
    float x2 = fminf(fmaxf(__fadd_rn(pcx, hx), 0.0f), 1023.0f);
    float y2 = fminf(fmaxf(__fadd_rn(pcy, hv), 0.0f), 1023.0f);
    float bw = __fadd_rn(__fsub_rn(x2, x1), 1.0f);
    float bh = __fadd_rn(__fsub_rn(y2, y1), 1.0f);
    *valid_out = (bw >= 16.0f) && (bh >= 16.0f);
    return make_float4(x1, y1, x2, y2);
}

__device__ __forceinline__ float box_area(float4 b) {
    return __fmul_rn(__fadd_rn(__fsub_rn(b.z, b.x), 1.0f),
                     __fadd_rn(__fsub_rn(b.w, b.y), 1.0f));
}

// ---------- decode: sortable score-high word only ----------
__global__ __launch_bounds__(256) void decode_kernel(
        const float* __restrict__ scores,
        const float* __restrict__ deltas,
        unsigned* __restrict__ uhigh) {
    int i = blockIdx.x * 256 + threadIdx.x;   // exactly NPROP threads
    bool valid;
    (void)decode_box(deltas, i, &valid);
    int a = i % 9, pos = i / 9;
    float fg = scores[(size_t)pos * 18 + 9 + a];
    float sc = valid ? fg : -__builtin_huge_valf();
    unsigned u = __float_as_uint(sc);
    u = (u & 0x80000000u) ? ~u : (u | 0x80000000u);   // sortable: bigger = better
    uhigh[i] = u;
}

// ---------- single block: LDS hist threshold + wave-aggregated compact ----------
__global__ __launch_bounds__(1024) void select_compact(
        const unsigned* __restrict__ uhigh,
        u64* __restrict__ sel,
        unsigned* __restrict__ nsel) {
    __shared__ unsigned hist[NB];      // 64 KB
    __shared__ unsigned strip[1024];
    __shared__ unsigned group[64];
    __shared__ unsigned thr_sh, cnt_sh;
    int t = threadIdx.x, lane = t & 63;
    #pragma unroll
    for (int r = 0; r < NB / 1024; ++r) hist[t + r * 1024] = 0;
    if (t == 0) cnt_sh = 0;
    __syncthreads();

    unsigned v[36];                    // NPROP/1024 == 36
    #pragma unroll
    for (int r = 0; r < 36; ++r) v[r] = uhigh[t + r * 1024];
    #pragma unroll
    for (int r = 0; r < 36; ++r) atomicAdd(&hist[v[r] >> 18], 1u);
    __syncthreads();

    unsigned s = 0;
    #pragma unroll
    for (int k = 0; k < 16; ++k) s += hist[t * 16 + k];
    strip[t] = s;
    __syncthreads();
    if (t < 64) {
        unsigned g = 0;
        #pragma unroll
        for (int k = 0; k < 16; ++k) g += strip[t * 16 + k];
        group[t] = g;
    }
    __syncthreads();
    if (t == 0) {
        unsigned acc = 0; int g = 63;
        while (g > 0 && acc + group[g] < TOPN) { acc += group[g]; --g; }
        int si = g * 16 + 15;
        while (si > g * 16 && acc + strip[si] < TOPN) { acc += strip[si]; --si; }
        int b = si * 16 + 15;
        while (b > si * 16 && acc + hist[b] < TOPN) { acc += hist[b]; --b; }
        thr_sh = (unsigned)b;
    }
    __syncthreads();
    unsigned thr = thr_sh << 18;       // count(uhigh >= thr) >= TOPN by construction
    #pragma unroll
    for (int r = 0; r < 36; ++r) {
        bool pred = (v[r] >= thr);
        u64 b = __ballot(pred);
        int nb = __popcll(b);
        unsigned base = 0;
        if (lane == 0 && nb) base = atomicAdd(&cnt_sh, (unsigned)nb);
        base = __shfl(base, 0, 64);
        if (pred) {
            unsigned p = base + (unsigned)__popcll(b & ((1ULL << lane) - 1ULL));
            if (p < MAXSEL)
                sel[p] = ((u64)v[r] << 32) |
                         (u64)(0xFFFFFFFFu - (unsigned)(t + r * 1024));
        }
    }
    __syncthreads();
    if (t == 0) *nsel = (cnt_sh > MAXSEL) ? MAXSEL : cnt_sh;
}

// ---------- exact rank by counting, inner dim split SPLIT ways, atomic-free ----------
__global__ __launch_bounds__(256) void rank_partial(
        const u64* __restrict__ sel,
        const unsigned* __restrict__ nsel,
        int* __restrict__ rank8) {
    __shared__ u64 tile[1024];
    int t = threadIdx.x;
    int j = blockIdx.x * 256 + t;
    int n = (int)*nsel;
    int T = (n + SPLIT - 1) / SPLIT;
    int lo = blockIdx.y * T;
    int hi = min(lo + T, n);
    u64 myk = (j < n) ? sel[j] : 0ULL;
    int rk = 0;
    for (int base = lo; base < hi; base += 1024) {
        int m = min(1024, hi - base);
        for (int q = t; q < m; q += 256) tile[q] = sel[base + q];
        __syncthreads();
        #pragma unroll 4
        for (int q = 0; q < m; ++q) rk += (tile[q] > myk) ? 1 : 0;
        __syncthreads();
    }
    rank8[blockIdx.y * MAXSEL + j] = rk;
}

// ---------- scatter to rank position, re-decoding the box ----------
__global__ __launch_bounds__(256) void scatter_top(
        const u64* __restrict__ sel,
        const unsigned* __restrict__ nsel,
        const int* __restrict__ rank8,
        const float* __restrict__ deltas,
        float4* __restrict__ topb,
        float* __restrict__ areas,
        unsigned* __restrict__ topu) {
    int j = blockIdx.x * 256 + threadIdx.x;
    int n = (int)*nsel;
    if (j >= n) return;
    int r = 0;
    #pragma unroll
    for (int s = 0; s < SPLIT; ++s) r += rank8[s * MAXSEL + j];
    if (r >= TOPN) return;
    u64 k = sel[j];
    unsigned idx = 0xFFFFFFFFu - (unsigned)(k & 0xFFFFFFFFull);
    bool valid;
    float4 b = decode_box(deltas, (int)idx, &valid);
    topb[r] = b;
    areas[r] = box_area(b);
    topu[r] = (unsigned)(k >> 32);
}

// ---------- grid-parallel IoU suppression bit matrix (j > i only) ----------
__global__ void nms_mask(const float4* __restrict__ boxes,
                         const float* __restrict__ areas,
                         u64* __restrict__ mask) {
    int rb = blockIdx.x, cb = blockIdx.y;
    if (cb < rb) return;                       // sub-diagonal words never read
    __shared__ float4 cbx[64];
    __shared__ float  car[64];
    int tid = threadIdx.x;
    int j0 = cb * 64;
    if (j0 + tid < TOPN) { cbx[tid] = boxes[j0 + tid]; car[tid] = areas[j0 + tid]; }
    __syncthreads();
    int i = rb * 64 + tid;
    if (i >= TOPN) return;
    float4 bi = boxes[i];
    float  ai = areas[i];
    u64 bits = 0ULL;
    int jmax = min(64, TOPN - j0);
    for (int jj = 0; jj < jmax; ++jj) {
        int j = j0 + jj;
        if (j <= i) continue;
        float4 bj = cbx[jj];
        float xx1 = fmaxf(bi.x, bj.x);
        float yy1 = fmaxf(bi.y, bj.y);
        float xx2 = fminf(bi.z, bj.z);
        float yy2 = fminf(bi.w, bj.w);
        float w = fmaxf(__fadd_rn(__fsub_rn(xx2, xx1), 1.0f), 0.0f);
        float h = fmaxf(__fadd_rn(__fsub_rn(yy2, yy1), 1.0f), 0.0f);
        float inter = __fmul_rn(w, h);
        float denom = __fsub_rn(__fadd_rn(ai, car[jj]), inter);
        float iou = inter / denom;              // IEEE-exact, matches numpy
        if (iou > 0.5f) bits |= (1ULL << jj);
    }
    mask[(size_t)i * NWORDS + cb] = bits;
}

// ---------- greedy scan: zero dependent global loads on the critical path ----------
// 1024 thr. Per 128-row round r: wave0 resolves from the prefetched 4-word
// diagonal tile (words 2r..2r+3), computes the URGENT suppression for the next
// round's words (2r+2..3) from tile words [2],[3] via an in-wave shfl-OR
// reduce (kept in registers), and does lane-parallel bookkeeping. Concurrently
// waves 1-14 LAZY-apply round r-1's kept rows to words >= 2r+2 (not read until
// round r+1's resolve reads rem | urgent regs; barrier-separated), and wave 15
// prefetches round r+1's diagonal tile + finite flags. -inf boxes suppress but
// are excluded from output (ref applies isfinite AFTER nms).
__global__ __launch_bounds__(1024) void nms_scan(
        const u64* __restrict__ mask,
        const unsigned* __restrict__ topu,
        const float4* __restrict__ topb,
        float* __restrict__ out) {
    __shared__ unsigned rem32[NWORDS * 2];
    __shared__ u64 diag[2][128][4];     // 8 KB
    __shared__ u64 Fsh[2][2];
    __shared__ short kept_rows[2][128];
    __shared__ short kept_list[POSTN];
    __shared__ int nk_sh[2];
    __shared__ int cnt_sh, stop_sh;

    int t = threadIdx.x, wave = t >> 6, lane = t & 63;
    if (t >= 640 && t < 640 + NWORDS * 2) rem32[t - 640] = 0;
    if (t >= 128 && t < 640) {          // round-0 tile: rows 0..127, words 0..3
        int idx = t - 128;
        diag[0][idx >> 2][idx & 3] = mask[(size_t)(idx >> 2) * NWORDS + (idx & 3)];
    }
    if (wave == 0) {
        u64 f = __ballot(topu[lane] != NEGINF_PAT);
        if (lane == 0) { Fsh[0][0] = f; cnt_sh = 0; stop_sh = 0; nk_sh[0] = 0; nk_sh[1] = 0; }
    } else if (wave == 1) {
        u64 f = __ballot(topu[64 + lane] != NEGINF_PAT);
        if (lane == 0) Fsh[0][1] = f;
    }
    __syncthreads();

    u64 urg0 = 0, urg1 = 0;   // wave0: urgent removed-bits for next round's 2 words

    for (int r = 0; r < NROUND; ++r) {
        int p = r & 1;
        int i0 = r * 128;
        if (wave == 0) {
            u64 r0w0 = diag[p][lane][0];
            u64 r0w1 = diag[p][lane][1];
            u64 r1w1 = diag[p][64 + lane][1];
            u64 R0 = ((u64)rem32[4 * r]     | ((u64)rem32[4 * r + 1] << 32)) | urg0;
            u64 R1 = ((u64)rem32[4 * r + 2] | ((u64)rem32[4 * r + 3] << 32)) | urg1;
            int nb = min(128, TOPN - i0);           // 128, or 112 on last round
            u64 v1 = (nb >= 128) ? ~0ULL : ((1ULL << (nb - 64)) - 1ULL);
            u64 a0 = ~R0;
            u64 a1 = ~R1 & v1;
            u64 k0 = 0ULL, k1 = 0ULL;
            while (a0) {
                int ii = __builtin_ctzll(a0);
                u64 bit = 1ULL << ii;
                k0 |= bit;
                u64 s0 = __shfl(r0w0, ii, 64);
                u64 s1 = __shfl(r0w1, ii, 64);
                a0 &= ~(s0 | bit);
                a1 &= ~s1;
            }
            while (a1) {
                int ii = __builtin_ctzll(a1);
                u64 bit = 1ULL << ii;
                k1 |= bit;
                u64 s1 = __shfl(r1w1, ii, 64);
                a1 &= ~(s1 | bit);
            }
            // lane-parallel bookkeeping
            u64 F0 = Fsh[p][0], F1 = Fsh[p][1];
            u64 kf0 = k0 & F0, kf1 = k1 & F1;
            int nk0 = __popcll(k0);
            int c0  = __popcll(kf0);
            int base = cnt_sh;
            u64 ltm = (1ULL << lane) - 1ULL;        // bits strictly below lane
            if ((k0 >> lane) & 1)
                kept_rows[p][__popcll(k0 & ltm)] = (short)(i0 + lane);
            if ((k1 >> lane) & 1)
                kept_rows[p][nk0 + __popcll(k1 & ltm)] = (short)(i0 + 64 + lane);
            if ((kf0 >> lane) & 1) {
                int pos = base + __popcll(kf0 & ltm);
                if (pos < POSTN) kept_list[pos] = (short)(i0 + lane);
            }
            if ((kf1 >> lane) & 1) {
                int pos = base + c0 + __popcll(kf1 & ltm);
                if (pos < POSTN) kept_list[pos] = (short)(i0 + 64 + lane);
            }
            // urgent for next round (words 2r+2..3) from tile words [2],[3]
            u64 a0u = 0ULL, a1u = 0ULL;
            if ((k0 >> lane) & 1) { a0u = diag[p][lane][2];       a1u = diag[p][lane][3]; }
            if ((k1 >> lane) & 1) { a0u |= diag[p][64 + lane][2]; a1u |= diag[p][64 + lane][3]; }
            #pragma unroll
            for (int off = 1; off < 64; off <<= 1) {
                a0u |= __shfl_xor(a0u, off, 64);
                a1u |= __shfl_xor(a1u, off, 64);
            }
            urg0 = a0u; urg1 = a1u;
            if (lane == 0) {
                nk_sh[p] = nk0 + __popcll(k1);
                int cc = base + c0 + __popcll(kf1);
                if (cc > POSTN) cc = POSTN;
                cnt_sh = cc;
                stop_sh = (cc >= POSTN) || (r == NROUND - 1);
            }
        } else if (wave == 15) {
            if (r + 1 < NROUND) {       // prefetch round r+1 tile + finite flags
                int i1 = i0 + 128;
                #pragma unroll
                for (int q = lane; q < 512; q += 64) {
                    int row = i1 + (q >> 2), k = q & 3;
                    int wd = 2 * (r + 1) + k;
                    diag[p ^ 1][q >> 2][k] = (row < TOPN && wd < NWORDS)
                        ? mask[(size_t)row * NWORDS + wd] : 0ULL;
                }
                u64 fa = __ballot((i1 + lane < TOPN) && (topu[i1 + lane] != NEGINF_PAT));
                u64 fb = __ballot((i1 + 64 + lane < TOPN) && (topu[i1 + 64 + lane] != NEGINF_PAT));
                if (lane == 0) { Fsh[p ^ 1][0] = fa; Fsh[p ^ 1][1] = fb; }
            }
        } else {
            // lazy apply: round r-1's kept rows, words >= 2r+2 (read at round r+2)
            int nkp = nk_sh[p ^ 1];
            int left = NWORDS - (2 * r + 2);
            if (r > 0 && nkp > 0 && left > 0) {
                int tot = nkp * left;
                for (int q = t - 64; q < tot; q += 896) {
                    int k  = q / left;
                    int wd = 2 * r + 2 + (q - k * left);
                    int row = kept_rows[p ^ 1][k];
                    u64 v = mask[(size_t)row * NWORDS + wd];
                    if (v) {
                        unsigned lo = (unsigned)v, hi = (unsigned)(v >> 32);
                        if (lo) atomicOr(&rem32[2 * wd],     lo);
                        if (hi) atomicOr(&rem32[2 * wd + 1], hi);
                    }
                }
            }
        }
        __syncthreads();
        if (stop_sh) break;
    }

    // fused output: first 300 kept (rank order), /1024, zero-fill rest
    if (t < POSTN) {
        float4 v = make_float4(0.f, 0.f, 0.f, 0.f);
        if (t < cnt_sh) {
            float4 b = topb[kept_list[t]];
            const float s = 0.0009765625f;   // 1/1024 (exact)
            v = make_float4(b.x * s, b.y * s, b.z * s, b.w * s);
        }
        ((float4*)out)[t] = v;
    }
}

extern "C" void kernel_launch(void* const* d_in, const int* in_sizes, int n_in,
                              void* d_out, int out_size, void* d_ws, size_t ws_size,
                              hipStream_t stream) {
    const float* scores = (const float*)d_in[0];   // (1,64,64,18)
    const float* deltas = (const float*)d_in[1];   // (1,64,64,36)
    float* out = (float*)d_out;                    // 300*4

    char* w = (char*)d_ws;
    unsigned* uhigh = (unsigned*)(w);               //       0 ..  147456
    u64*      sel   = (u64*)(w + 147456);           //  147456 ..  212992
    unsigned* nsel  = (unsigned*)(w + 212992);      //  212992 ..  213008
    int*      rank8 = (int*)(w + 213008);           //  213008 ..  475152
    float4*   topb  = (float4*)(w + 475152);        //  475152 ..  571152
    float*    areas = (float*)(w + 571152);         //  571152 ..  595152
    unsigned* topu  = (unsigned*)(w + 595152);      //  595152 ..  619152
    u64*      mask  = (u64*)(w + 619152);           //  619152 .. 5131152 (4.5 MB)

    decode_kernel<<<NPROP / 256, 256, 0, stream>>>(scores, deltas, uhigh);
    select_compact<<<1, 1024, 0, stream>>>(uhigh, sel, nsel);
    rank_partial<<<dim3(MAXSEL / 256, SPLIT), 256, 0, stream>>>(sel, nsel, rank8);
    scatter_top<<<MAXSEL / 256, 256, 0, stream>>>(sel, nsel, rank8, deltas, topb, areas, topu);
    nms_mask<<<dim3(NWORDS, NWORDS), 64, 0, stream>>>(topb, areas, mask);
    nms_scan<<<1, 1024, 0, stream>>>(mask, topu, topb, out);
}